// Round 4
// baseline (139.078 us; speedup 1.0000x reference)
//
#include <hip/hip_runtime.h>
#include <math.h>

#define N_ROWS 4096
#define DIM    128
#define A_LAB  512
#define INV_TAU 14.285714285714286f

typedef __attribute__((ext_vector_type(8))) short short8;   // 8 bf16 (4 VGPRs)
typedef __attribute__((ext_vector_type(4))) float f32x4;    // MFMA C/D frag (16x16)
typedef __attribute__((ext_vector_type(4))) int i32x4;      // i8 MFMA A/B frag
typedef __attribute__((ext_vector_type(16))) int i32x16;    // i8 MFMA C/D frag (32x32)

// ---------------- workspace layout (bytes) ----------------
// zbf   u16 [8192*128]   @ 0          (2,097,152)
// labs8 i8  [4096*512]   @ 2,097,152  (2,097,152)
// s     i32 [4096]       @ 4,194,304  (16,384)
// pm    u32 [4096*128]   @ 4,210,688  (2,097,152)
// part  f32 [64*3*4096]  @ 6,307,840  (3,145,728)   total ~9.45 MB

__device__ __forceinline__ unsigned short f2bf(float f) {
  unsigned int u = __builtin_bit_cast(unsigned int, f);
  u += 0x7fffu + ((u >> 16) & 1u);            // round-to-nearest-even
  return (unsigned short)(u >> 16);
}

// ------------ kernel 1: L2-normalize (-> bf16) + labels -> i8 + row-popcount ------------
__global__ __launch_bounds__(256) void k_norm_pack(
    const float* __restrict__ z1, const float* __restrict__ z2,
    const int* __restrict__ labels,
    unsigned int* __restrict__ zbf, unsigned char* __restrict__ labs8,
    int* __restrict__ s, float* __restrict__ out)
{
  if (blockIdx.x == 0 && threadIdx.x == 0) out[0] = 0.0f;  // k_loss atomically adds
  const int wave = threadIdx.x >> 6, lane = threadIdx.x & 63;
  const int r = blockIdx.x * 4 + wave;         // 0..8191
  const float* src = (r < N_ROWS) ? (z1 + (size_t)r * DIM)
                                  : (z2 + (size_t)(r - N_ROWS) * DIM);
  float2 x = ((const float2*)src)[lane];
  float ss = x.x * x.x + x.y * x.y;
  #pragma unroll
  for (int off = 32; off > 0; off >>= 1) ss += __shfl_xor(ss, off);
  const float inv = 1.0f / fmaxf(sqrtf(ss), 1e-12f);
  const unsigned int lo = f2bf(x.x * inv);
  const unsigned int hi = f2bf(x.y * inv);
  zbf[(size_t)r * 64 + lane] = (hi << 16) | lo;

  if (r < N_ROWS) {
    const int4* lp = (const int4*)(labels + (size_t)r * A_LAB);
    const int4 a = lp[2 * lane], b = lp[2 * lane + 1];
    const unsigned int w0 = (unsigned int)(a.x != 0)       | ((unsigned int)(a.y != 0) << 8)
                          | ((unsigned int)(a.z != 0) << 16) | ((unsigned int)(a.w != 0) << 24);
    const unsigned int w1 = (unsigned int)(b.x != 0)       | ((unsigned int)(b.y != 0) << 8)
                          | ((unsigned int)(b.z != 0) << 16) | ((unsigned int)(b.w != 0) << 24);
    uint2 v; v.x = w0; v.y = w1;
    ((uint2*)labs8)[(size_t)r * 64 + lane] = v;   // 8 bytes per thread, row = 512 B
    int cnt = __popc(w0) + __popc(w1);            // bytes are 0/1 -> popc == byte sum
    #pragma unroll
    for (int off = 32; off > 0; off >>= 1) cnt += __shfl_xor(cnt, off);
    if (lane == 0) s[r] = cnt;
  }
}

// ------------ kernel 2: Jaccard positive mask, triangular (both (i,j) and (j,i)) ------------
// inter[i][j] = labs8[i] . labs8[j]  (K=512 bytes, i8->i32, exact)
// pos bit: jac >= 0.3  <=>  13*inter >= 3*(s_i + s_j)
// 528 blocks = upper-triangular 32x32 tile pairs. Per block: stage I-tile + J-tile
// (2 K-chunks of 256 B, 64 KB LDS), compute acc_ij AND acc_ji by swapping operands.
// LDS rows: 16 units of 16 B, unit (r,u) -> r*16 + (u ^ (r&15)).
// mfma_i32_32x32x32_i8: A/B frag = 16 k-bytes at [m=lane&31][kb=32*ks+16*(lane>>5)];
// C/D: col=lane&31, row=(reg&3)+8*(reg>>2)+4*(lane>>5).
__global__ __launch_bounds__(256, 2) void k_jac(
    const unsigned char* __restrict__ labs8, const int* __restrict__ s,
    unsigned int* __restrict__ pm)
{
  __shared__ uint4 lds[4096];                 // I units [0,2048), J units [2048,4096)
  const int tid = threadIdx.x;
  int t = blockIdx.x, bi = 0;                 // triangular decode: bi <= bj
  while (t >= 32 - bi) { t -= 32 - bi; ++bi; }
  const int bj = bi + t;
  const int ibase = bi * 128, jbase = bj * 128;
  const int wave = tid >> 6, lane = tid & 63;
  const int wrow = (wave >> 1) * 64, wcol = (wave & 1) * 64;
  const int col = lane & 31, h = lane >> 5;

  i32x16 aij[2][2], aji[2][2];
  #pragma unroll
  for (int rt = 0; rt < 2; ++rt)
    #pragma unroll
    for (int nt = 0; nt < 2; ++nt)
      #pragma unroll
      for (int e = 0; e < 16; ++e) { aij[rt][nt][e] = 0; aji[rt][nt][e] = 0; }

  for (int ck = 0; ck < 2; ++ck) {            // K chunks of 256 bytes
    __syncthreads();
    #pragma unroll
    for (int p = 0; p < 8; ++p) {
      const int g = p * 256 + tid;            // 0..2047 units
      const int r = g >> 4, u = g & 15;
      const int d = r * 16 + (u ^ (r & 15));
      lds[d]        = *(const uint4*)(labs8 + (((size_t)(ibase + r)) << 9) + ck * 256 + u * 16);
      lds[2048 + d] = *(const uint4*)(labs8 + (((size_t)(jbase + r)) << 9) + ck * 256 + u * 16);
    }
    __syncthreads();

    #pragma unroll
    for (int ks = 0; ks < 8; ++ks) {          // 32 k-bytes per step
      const int u = ks * 2 + h;
      i32x4 fiw[2], fjw[2], fic[2], fjc[2];
      #pragma unroll
      for (int rt = 0; rt < 2; ++rt) {
        const int m = wrow + rt * 32 + col;
        const int o = m * 16 + (u ^ (m & 15));
        fiw[rt] = *(const i32x4*)&lds[o];
        fjw[rt] = *(const i32x4*)&lds[2048 + o];
      }
      #pragma unroll
      for (int nt = 0; nt < 2; ++nt) {
        const int m = wcol + nt * 32 + col;
        const int o = m * 16 + (u ^ (m & 15));
        fic[nt] = *(const i32x4*)&lds[o];
        fjc[nt] = *(const i32x4*)&lds[2048 + o];
      }
      #pragma unroll
      for (int rt = 0; rt < 2; ++rt)
        #pragma unroll
        for (int nt = 0; nt < 2; ++nt) {
          aij[rt][nt] = __builtin_amdgcn_mfma_i32_32x32x32_i8(fiw[rt], fjc[nt], aij[rt][nt], 0, 0, 0);
          aji[rt][nt] = __builtin_amdgcn_mfma_i32_32x32x32_i8(fjw[rt], fic[nt], aji[rt][nt], 0, 0, 0);
        }
    }
  }

  // ---- epilogue: threshold + ballot -> pm words, for (I,J) and mirrored (J,I) ----
  #pragma unroll
  for (int side = 0; side < 2; ++side) {
    const int rbase = side ? jbase : ibase;   // rows of this output block
    const int cbase = side ? ibase : jbase;   // cols of this output block
    int sj[2];
    #pragma unroll
    for (int nt = 0; nt < 2; ++nt) sj[nt] = s[cbase + wcol + nt * 32 + col];
    #pragma unroll
    for (int rt = 0; rt < 2; ++rt) {
      int si[16];
      #pragma unroll
      for (int reg = 0; reg < 16; ++reg) {
        const int row = (reg & 3) + 8 * (reg >> 2) + 4 * h;
        si[reg] = s[rbase + wrow + rt * 32 + row];
      }
      #pragma unroll
      for (int nt = 0; nt < 2; ++nt) {
        const int w = (cbase + wcol + nt * 32) >> 5;
        #pragma unroll
        for (int reg = 0; reg < 16; ++reg) {
          const int inter = side ? aji[rt][nt][reg] : aij[rt][nt][reg];
          const bool pred = 13 * inter >= 3 * (si[reg] + sj[nt]);
          const unsigned long long bal = __ballot(pred);
          const int r0 = (reg & 3) + 8 * (reg >> 2);
          const int i0 = rbase + wrow + rt * 32 + r0;
          if (lane == 0)      pm[(size_t)i0 * 128 + w]       = (unsigned int)bal;
          else if (lane == 1) pm[(size_t)(i0 + 4) * 128 + w] = (unsigned int)(bal >> 32);
        }
      }
    }
  }
}

// ---------------- kernel 3: MFMA sim-GEMM + fused masked-softmax partials ------
__global__ __launch_bounds__(256, 2) void k_main(
    const unsigned short* __restrict__ zbf, const unsigned int* __restrict__ pm,
    float* __restrict__ part)
{
  __shared__ unsigned short lds[2 * 128 * 128];  // A @0 (32KB), B @128*128 (32KB)
  const int tid = threadIdx.x;
  const int abase = blockIdx.x * 128;   // 32 anchor tiles
  const int cbase = blockIdx.y * 128;   // 64 column tiles over 2N

  {
    const uint4* gA = (const uint4*)(zbf + (size_t)abase * 128);
    const uint4* gB = (const uint4*)(zbf + (size_t)cbase * 128);
    uint4* sA = (uint4*)lds;
    uint4* sB = (uint4*)(lds + 128 * 128);
    #pragma unroll
    for (int p = 0; p < 8; ++p) {
      const int g = p * 256 + tid;       // 0..2047 units
      const int r = g >> 4, u = g & 15;
      const int d = r * 16 + (u ^ (r & 15));
      sA[d] = gA[g];
      sB[d] = gB[g];
    }
  }
  __syncthreads();

  const int wave = tid >> 6, lane = tid & 63;
  const int col = lane & 15, quad = lane >> 4;
  const int wrow = wave * 32;                    // this wave: rows [wrow, wrow+32)
  const uint4* sAu = (const uint4*)lds;
  const uint4* sBu = (const uint4*)(lds + 128 * 128);

  short8 afr[2][4];
  #pragma unroll
  for (int rt = 0; rt < 2; ++rt)
    #pragma unroll
    for (int kf = 0; kf < 4; ++kf) {
      const int r = wrow + rt * 16 + col;
      const int u = kf * 4 + quad;
      afr[rt][kf] = *(const short8*)&sAu[r * 16 + (u ^ (r & 15))];
    }

  f32x4 acc[2][8];
  #pragma unroll
  for (int rt = 0; rt < 2; ++rt)
    #pragma unroll
    for (int nt = 0; nt < 8; ++nt) acc[rt][nt] = (f32x4){0, 0, 0, 0};

  #pragma unroll
  for (int nt = 0; nt < 8; ++nt) {
    short8 bfr[4];
    #pragma unroll
    for (int kf = 0; kf < 4; ++kf) {
      const int r = nt * 16 + col;
      const int u = kf * 4 + quad;
      bfr[kf] = *(const short8*)&sBu[r * 16 + (u ^ (r & 15))];
    }
    #pragma unroll
    for (int rt = 0; rt < 2; ++rt)
      #pragma unroll
      for (int kf = 0; kf < 4; ++kf)
        acc[rt][nt] = __builtin_amdgcn_mfma_f32_16x16x32_bf16(
            afr[rt][kf], bfr[kf], acc[rt][nt], 0, 0, 0);
  }

  // ---- epilogue: fixed shift m = 1/tau (loss shift-invariant); skip self col ----
  const bool left = (cbase < N_ROWS);            // block-uniform
  const int cw0 = (cbase & (N_ROWS - 1)) >> 5;   // first of 4 pm words for this tile
  float lacc[2][4], Sacc[2][4], Pcnt[2][4];
  #pragma unroll
  for (int rt = 0; rt < 2; ++rt)
    #pragma unroll
    for (int reg = 0; reg < 4; ++reg) { lacc[rt][reg] = 0; Sacc[rt][reg] = 0; Pcnt[rt][reg] = 0; }

  #pragma unroll
  for (int rt = 0; rt < 2; ++rt) {
    unsigned int pw[4][4];
    #pragma unroll
    for (int reg = 0; reg < 4; ++reg) {
      const int i = abase + wrow + rt * 16 + quad * 4 + reg;
      #pragma unroll
      for (int w = 0; w < 4; ++w) pw[reg][w] = pm[(size_t)i * 128 + cw0 + w];
    }
    #pragma unroll
    for (int nt = 0; nt < 8; ++nt) {
      const int j = cbase + nt * 16 + col;
      const int jc = j & (N_ROWS - 1);
      const int bitpos = jc & 31;
      const int w = nt >> 1;
      #pragma unroll
      for (int reg = 0; reg < 4; ++reg) {
        const int i = abase + wrow + rt * 16 + quad * 4 + reg;
        const float d = acc[rt][nt][reg];
        const bool bit = (pw[reg][w] >> bitpos) & 1;
        const bool self = left && (j == i);
        const bool pos = left ? (bit && !self) : (bit || (jc == i));
        const float e = __expf((d - 1.0f) * INV_TAU);
        if (!self) lacc[rt][reg] += e;
        if (pos) { Sacc[rt][reg] += d; Pcnt[rt][reg] += 1.0f; }
      }
    }
  }

  // ---- reduce across the 16 col-lanes, write per-slice partials ----
  #pragma unroll
  for (int rt = 0; rt < 2; ++rt)
    #pragma unroll
    for (int reg = 0; reg < 4; ++reg) {
      float l = lacc[rt][reg], S = Sacc[rt][reg], P = Pcnt[rt][reg];
      #pragma unroll
      for (int m = 1; m < 16; m <<= 1) {
        l += __shfl_xor(l, m);
        S += __shfl_xor(S, m);
        P += __shfl_xor(P, m);
      }
      if (col == 0) {
        const int i = abase + wrow + rt * 16 + quad * 4 + reg;
        float* base = part + (size_t)blockIdx.y * 3 * 4096;
        base[i] = l;
        base[4096 + i] = S;
        base[8192 + i] = P;
      }
    }
}

// ---------------- kernel 4: per-anchor loss + atomic final reduce ----------------
__global__ __launch_bounds__(128) void k_loss(
    const float* __restrict__ part, float* __restrict__ out)
{
  const int a = blockIdx.x * 128 + threadIdx.x;   // 0..4095
  float l = 0.0f, S = 0.0f, P = 0.0f;
  #pragma unroll 8
  for (int by = 0; by < 64; ++by) {
    const float* b = part + (size_t)by * 3 * 4096;
    l += b[a];
    S += b[4096 + a];
    P += b[8192 + a];
  }
  const float np = fmaxf(P, 1.0f);
  float v = INV_TAU + logf(l + 1e-8f) - (S * INV_TAU) / np;
  #pragma unroll
  for (int off = 32; off > 0; off >>= 1) v += __shfl_xor(v, off);
  __shared__ float ws2[2];
  const int wave = threadIdx.x >> 6, lane = threadIdx.x & 63;
  if (lane == 0) ws2[wave] = v;
  __syncthreads();
  if (threadIdx.x == 0) atomicAdd(out, (ws2[0] + ws2[1]) * (1.0f / (float)N_ROWS));
}

extern "C" void kernel_launch(void* const* d_in, const int* in_sizes, int n_in,
                              void* d_out, int out_size, void* d_ws, size_t ws_size,
                              hipStream_t stream) {
  const float* z1 = (const float*)d_in[0];
  const float* z2 = (const float*)d_in[1];
  const int* labels = (const int*)d_in[2];
  float* out = (float*)d_out;
  char* ws = (char*)d_ws;

  unsigned int* zbf    = (unsigned int*)(ws);
  unsigned char* labs8 = (unsigned char*)(ws + 2097152);
  int* s               = (int*)(ws + 4194304);
  unsigned int* pm     = (unsigned int*)(ws + 4210688);
  float* part          = (float*)(ws + 6307840);

  hipLaunchKernelGGL(k_norm_pack, dim3(2048), dim3(256), 0, stream,
                     z1, z2, labels, zbf, labs8, s, out);
  hipLaunchKernelGGL(k_jac, dim3(528), dim3(256), 0, stream,
                     labs8, s, pm);
  hipLaunchKernelGGL(k_main, dim3(32, 64), dim3(256), 0, stream,
                     (const unsigned short*)zbf, pm, part);
  hipLaunchKernelGGL(k_loss, dim3(32), dim3(128), 0, stream, part, out);
}

// Round 5
// 128.300 us; speedup vs baseline: 1.0840x; 1.0840x over previous
//
#include <hip/hip_runtime.h>
#include <math.h>

#define N_ROWS 4096
#define DIM    128
#define A_LAB  512
#define INV_TAU 14.285714285714286f

typedef __attribute__((ext_vector_type(8))) short short8;   // 8 bf16 (4 VGPRs)
typedef __attribute__((ext_vector_type(4))) float f32x4;    // MFMA C/D frag (16x16)
typedef __attribute__((ext_vector_type(4))) int i32x4;      // i8 MFMA A/B frag
typedef __attribute__((ext_vector_type(16))) int i32x16;    // i8 MFMA C/D frag (32x32)

// ---------------- workspace layout (bytes) ----------------
// zbf   u16 [8192*128]   @ 0          (2,097,152)  unit-permuted (see k_norm_pack)
// labs8 i8  [4096*512]   @ 2,097,152  (2,097,152)  unit-permuted (see k_norm_pack)
// s     i32 [4096]       @ 4,194,304  (16,384)
// pm    u32 [4096*128]   @ 4,210,688  (2,097,152)
// part  f32 [64*3*4096]  @ 6,307,840  (3,145,728)   total ~9.45 MB

__device__ __forceinline__ unsigned short f2bf(float f) {
  unsigned int u = __builtin_bit_cast(unsigned int, f);
  u += 0x7fffu + ((u >> 16) & 1u);            // round-to-nearest-even
  return (unsigned short)(u >> 16);
}

// async global->LDS DMA, 16 B/lane; LDS dest = wave-uniform base + lane*16
__device__ __forceinline__ void gl_lds16(const void* g, void* l) {
  __builtin_amdgcn_global_load_lds(
      (const __attribute__((address_space(1))) unsigned int*)g,
      (__attribute__((address_space(3))) unsigned int*)l, 16, 0, 0);
}

// ------------ kernel 1: L2-normalize (-> bf16) + labels -> i8 + row-popcount ------------
// zbf rows are 16 units of 16 B, stored PERMUTED: content of unit U lands at slot
// U ^ (r&15). labs8 rows are 32 units, permuted within each 8-unit chunk:
// content (c,u) lands at slot (c, u ^ (r&7)). Linear global_load_lds copies then
// reproduce the XOR-swizzled LDS layout the readers expect.
__global__ __launch_bounds__(256) void k_norm_pack(
    const float* __restrict__ z1, const float* __restrict__ z2,
    const int* __restrict__ labels,
    unsigned int* __restrict__ zbf, uint2* __restrict__ labs8,
    int* __restrict__ s, float* __restrict__ out)
{
  if (blockIdx.x == 0 && threadIdx.x == 0) out[0] = 0.0f;  // k_loss atomically adds
  const int wave = threadIdx.x >> 6, lane = threadIdx.x & 63;
  const int r = blockIdx.x * 4 + wave;         // 0..8191
  const float* src = (r < N_ROWS) ? (z1 + (size_t)r * DIM)
                                  : (z2 + (size_t)(r - N_ROWS) * DIM);
  float2 x = ((const float2*)src)[lane];
  float ss = x.x * x.x + x.y * x.y;
  #pragma unroll
  for (int off = 32; off > 0; off >>= 1) ss += __shfl_xor(ss, off);
  const float inv = 1.0f / fmaxf(sqrtf(ss), 1e-12f);
  const unsigned int lo = f2bf(x.x * inv);
  const unsigned int hi = f2bf(x.y * inv);
  {
    const int U  = lane >> 2;                  // source 16B unit 0..15
    const int Up = U ^ (r & 15);               // permuted slot
    zbf[(size_t)r * 64 + Up * 4 + (lane & 3)] = (hi << 16) | lo;
  }

  if (r < N_ROWS) {
    const int4* lp = (const int4*)(labels + (size_t)r * A_LAB);
    const int4 a = lp[2 * lane], b = lp[2 * lane + 1];
    const unsigned int w0 = (unsigned int)(a.x != 0)       | ((unsigned int)(a.y != 0) << 8)
                          | ((unsigned int)(a.z != 0) << 16) | ((unsigned int)(a.w != 0) << 24);
    const unsigned int w1 = (unsigned int)(b.x != 0)       | ((unsigned int)(b.y != 0) << 8)
                          | ((unsigned int)(b.z != 0) << 16) | ((unsigned int)(b.w != 0) << 24);
    uint2 v; v.x = w0; v.y = w1;
    const int Ul  = lane >> 1;                 // source unit 0..31
    const int cc  = Ul >> 3, uu = Ul & 7;
    const int Ulp = (cc << 3) | (uu ^ (r & 7));
    labs8[(size_t)r * 64 + Ulp * 2 + (lane & 1)] = v;
    int cnt = __popc(w0) + __popc(w1);         // bytes are 0/1 -> popc == byte sum
    #pragma unroll
    for (int off = 32; off > 0; off >>= 1) cnt += __shfl_xor(cnt, off);
    if (lane == 0) s[r] = cnt;
  }
}

// ------------ kernel 2: Jaccard positive mask via i8 MFMA GEMM ------------
// inter[i][j] = labs8[i] . labs8[j]  (K=512 bytes, i8->i32, exact)
// pos bit: jac >= 0.3  <=>  13*inter >= 3*(s_i + s_j)
// 32x32 grid of 128x128 tiles; 4 waves in 2x2; wave = 2x2 subtiles of 32x32.
// Double-buffered LDS (2 x 32 KB), async global_load_lds staging, prefetch ck+1
// before computing ck. LDS unit (r,u) at r*8 + (u ^ (r&7)) -- produced by the
// linear DMA because labs8 is pre-permuted.
// mfma_i32_32x32x32_i8 C/D: col=lane&31, row=(reg&3)+8*(reg>>2)+4*(lane>>5).
__global__ __launch_bounds__(256, 2) void k_jac(
    const unsigned char* __restrict__ labs8, const int* __restrict__ s,
    unsigned int* __restrict__ pm)
{
  __shared__ uint4 lds[4096];   // [buf(2)][tile I/J][1024 units]
  const int tid = threadIdx.x;
  const int ibase = blockIdx.x * 128, jbase = blockIdx.y * 128;
  const int wave = tid >> 6, lane = tid & 63;
  const int wrow = (wave >> 1) * 64, wcol = (wave & 1) * 64;
  const int col = lane & 31, h = lane >> 5;

  // per-lane s-cache for the epilogue (fetched later via __shfl)
  const int s3i = 3 * s[ibase + wrow + lane];
  const int s3j = 3 * s[jbase + wcol + lane];

  // stage chunk 0 into buffer 0
  #pragma unroll
  for (int it = 0; it < 4; ++it) {
    const int g = wave * 256 + it * 64 + lane;   // linear unit 0..1023
    const int r = g >> 3, u = g & 7;
    gl_lds16(labs8 + (((size_t)(ibase + r)) << 9) + u * 16,
             &lds[wave * 256 + it * 64]);
    gl_lds16(labs8 + (((size_t)(jbase + r)) << 9) + u * 16,
             &lds[1024 + wave * 256 + it * 64]);
  }
  __syncthreads();

  i32x16 acc[2][2];
  #pragma unroll
  for (int rt = 0; rt < 2; ++rt)
    #pragma unroll
    for (int nt = 0; nt < 2; ++nt)
      #pragma unroll
      for (int e = 0; e < 16; ++e) acc[rt][nt][e] = 0;

  for (int ck = 0; ck < 4; ++ck) {            // K chunks of 128 bytes
    const int cur = (ck & 1) * 2048;
    if (ck < 3) {                             // prefetch next chunk into other buf
      const int nxt = ((ck + 1) & 1) * 2048;
      #pragma unroll
      for (int it = 0; it < 4; ++it) {
        const int g = wave * 256 + it * 64 + lane;
        const int r = g >> 3, u = g & 7;
        const size_t go = (size_t)(ck + 1) * 128 + u * 16;
        gl_lds16(labs8 + (((size_t)(ibase + r)) << 9) + go,
                 &lds[nxt + wave * 256 + it * 64]);
        gl_lds16(labs8 + (((size_t)(jbase + r)) << 9) + go,
                 &lds[nxt + 1024 + wave * 256 + it * 64]);
      }
    }
    #pragma unroll
    for (int ks = 0; ks < 4; ++ks) {          // 32 k-bytes per step
      const int u = ks * 2 + h;
      i32x4 a[2], b[2];
      #pragma unroll
      for (int rt = 0; rt < 2; ++rt) {
        const int m = wrow + rt * 32 + col;
        a[rt] = *(const i32x4*)&lds[cur + m * 8 + (u ^ (m & 7))];
      }
      #pragma unroll
      for (int nt = 0; nt < 2; ++nt) {
        const int m = wcol + nt * 32 + col;
        b[nt] = *(const i32x4*)&lds[cur + 1024 + m * 8 + (u ^ (m & 7))];
      }
      #pragma unroll
      for (int rt = 0; rt < 2; ++rt)
        #pragma unroll
        for (int nt = 0; nt < 2; ++nt)
          acc[rt][nt] = __builtin_amdgcn_mfma_i32_32x32x32_i8(a[rt], b[nt], acc[rt][nt], 0, 0, 0);
    }
    if (ck < 3) __syncthreads();
  }

  // ---- epilogue: threshold + ballot -> pm u32 words (s via shuffles, no global) ----
  #pragma unroll
  for (int rt = 0; rt < 2; ++rt)
    #pragma unroll
    for (int nt = 0; nt < 2; ++nt) {
      const int w = (jbase + wcol + nt * 32) >> 5;
      const int sj = __shfl(s3j, nt * 32 + col);
      #pragma unroll
      for (int reg = 0; reg < 16; ++reg) {
        const int r0 = (reg & 3) + 8 * (reg >> 2);
        const int si = __shfl(s3i, rt * 32 + r0 + 4 * h);
        const bool pred = 13 * acc[rt][nt][reg] >= si + sj;
        const unsigned long long bal = __ballot(pred);
        const int i0 = ibase + wrow + rt * 32 + r0;
        if (lane == 0)      pm[(size_t)i0 * 128 + w]       = (unsigned int)bal;
        else if (lane == 1) pm[(size_t)(i0 + 4) * 128 + w] = (unsigned int)(bal >> 32);
      }
    }
}

// ---------------- kernel 3: MFMA sim-GEMM + fused masked-softmax partials ------
// LDS unit (r,u) at r*16 + (u ^ (r&15)) -- produced by linear DMA from the
// pre-permuted zbf. MFMA 16x16x32 bf16; C/D: col=lane&15, row=quad*4+reg.
__global__ __launch_bounds__(256, 2) void k_main(
    const unsigned short* __restrict__ zbf, const unsigned int* __restrict__ pm,
    float* __restrict__ part)
{
  __shared__ unsigned short lds[2 * 128 * 128];  // A @0 (32KB), B @32KB
  uint4* sU = (uint4*)lds;                       // A units [0,2048), B [2048,4096)
  const int tid = threadIdx.x;
  const int abase = blockIdx.x * 128;   // 32 anchor tiles
  const int cbase = blockIdx.y * 128;   // 64 column tiles over 2N
  const int wave = tid >> 6, lane = tid & 63;

  {
    const char* gz = (const char*)zbf;
    #pragma unroll
    for (int it = 0; it < 8; ++it) {
      const int g = wave * 512 + it * 64 + lane;   // linear unit 0..2047
      const int r = g >> 4, u = g & 15;
      gl_lds16(gz + (size_t)(abase + r) * 256 + u * 16, &sU[wave * 512 + it * 64]);
      gl_lds16(gz + (size_t)(cbase + r) * 256 + u * 16, &sU[2048 + wave * 512 + it * 64]);
    }
  }
  __syncthreads();

  const int col = lane & 15, quad = lane >> 4;
  const int wrow = wave * 32;                    // this wave: rows [wrow, wrow+32)
  const uint4* sAu = sU;
  const uint4* sBu = sU + 2048;

  short8 afr[2][4];
  #pragma unroll
  for (int rt = 0; rt < 2; ++rt)
    #pragma unroll
    for (int kf = 0; kf < 4; ++kf) {
      const int r = wrow + rt * 16 + col;
      const int u = kf * 4 + quad;
      afr[rt][kf] = *(const short8*)&sAu[r * 16 + (u ^ (r & 15))];
    }

  f32x4 acc[2][8];
  #pragma unroll
  for (int rt = 0; rt < 2; ++rt)
    #pragma unroll
    for (int nt = 0; nt < 8; ++nt) acc[rt][nt] = (f32x4){0, 0, 0, 0};

  #pragma unroll
  for (int nt = 0; nt < 8; ++nt) {
    short8 bfr[4];
    #pragma unroll
    for (int kf = 0; kf < 4; ++kf) {
      const int r = nt * 16 + col;
      const int u = kf * 4 + quad;
      bfr[kf] = *(const short8*)&sBu[r * 16 + (u ^ (r & 15))];
    }
    #pragma unroll
    for (int rt = 0; rt < 2; ++rt)
      #pragma unroll
      for (int kf = 0; kf < 4; ++kf)
        acc[rt][nt] = __builtin_amdgcn_mfma_f32_16x16x32_bf16(
            afr[rt][kf], bfr[kf], acc[rt][nt], 0, 0, 0);
  }

  // ---- epilogue: fixed shift m = 1/tau (loss shift-invariant); skip self col ----
  const bool left = (cbase < N_ROWS);            // block-uniform
  const int cw0 = (cbase & (N_ROWS - 1)) >> 5;   // first of 4 pm words for this tile
  float lacc[2][4], Sacc[2][4], Pcnt[2][4];
  #pragma unroll
  for (int rt = 0; rt < 2; ++rt)
    #pragma unroll
    for (int reg = 0; reg < 4; ++reg) { lacc[rt][reg] = 0; Sacc[rt][reg] = 0; Pcnt[rt][reg] = 0; }

  #pragma unroll
  for (int rt = 0; rt < 2; ++rt) {
    unsigned int pw[4][4];
    #pragma unroll
    for (int reg = 0; reg < 4; ++reg) {
      const int i = abase + wrow + rt * 16 + quad * 4 + reg;
      #pragma unroll
      for (int w = 0; w < 4; ++w) pw[reg][w] = pm[(size_t)i * 128 + cw0 + w];
    }
    #pragma unroll
    for (int nt = 0; nt < 8; ++nt) {
      const int j = cbase + nt * 16 + col;
      const int jc = j & (N_ROWS - 1);
      const int bitpos = jc & 31;
      const int w = nt >> 1;
      #pragma unroll
      for (int reg = 0; reg < 4; ++reg) {
        const int i = abase + wrow + rt * 16 + quad * 4 + reg;
        const float d = acc[rt][nt][reg];
        const bool bit = (pw[reg][w] >> bitpos) & 1;
        const bool self = left && (j == i);
        const bool pos = left ? (bit && !self) : (bit || (jc == i));
        const float e = __expf((d - 1.0f) * INV_TAU);
        if (!self) lacc[rt][reg] += e;
        if (pos) { Sacc[rt][reg] += d; Pcnt[rt][reg] += 1.0f; }
      }
    }
  }

  // ---- reduce across the 16 col-lanes, write per-slice partials ----
  #pragma unroll
  for (int rt = 0; rt < 2; ++rt)
    #pragma unroll
    for (int reg = 0; reg < 4; ++reg) {
      float l = lacc[rt][reg], S = Sacc[rt][reg], P = Pcnt[rt][reg];
      #pragma unroll
      for (int m = 1; m < 16; m <<= 1) {
        l += __shfl_xor(l, m);
        S += __shfl_xor(S, m);
        P += __shfl_xor(P, m);
      }
      if (col == 0) {
        const int i = abase + wrow + rt * 16 + quad * 4 + reg;
        float* base = part + (size_t)blockIdx.y * 3 * 4096;
        base[i] = l;
        base[4096 + i] = S;
        base[8192 + i] = P;
      }
    }
}

// ---------------- kernel 4: per-anchor loss + atomic final reduce ----------------
__global__ __launch_bounds__(128) void k_loss(
    const float* __restrict__ part, float* __restrict__ out)
{
  const int a = blockIdx.x * 128 + threadIdx.x;   // 0..4095
  float l = 0.0f, S = 0.0f, P = 0.0f;
  #pragma unroll 8
  for (int by = 0; by < 64; ++by) {
    const float* b = part + (size_t)by * 3 * 4096;
    l += b[a];
    S += b[4096 + a];
    P += b[8192 + a];
  }
  const float np = fmaxf(P, 1.0f);
  float v = INV_TAU + logf(l + 1e-8f) - (S * INV_TAU) / np;
  #pragma unroll
  for (int off = 32; off > 0; off >>= 1) v += __shfl_xor(v, off);
  __shared__ float ws2[2];
  const int wave = threadIdx.x >> 6, lane = threadIdx.x & 63;
  if (lane == 0) ws2[wave] = v;
  __syncthreads();
  if (threadIdx.x == 0) atomicAdd(out, (ws2[0] + ws2[1]) * (1.0f / (float)N_ROWS));
}

extern "C" void kernel_launch(void* const* d_in, const int* in_sizes, int n_in,
                              void* d_out, int out_size, void* d_ws, size_t ws_size,
                              hipStream_t stream) {
  const float* z1 = (const float*)d_in[0];
  const float* z2 = (const float*)d_in[1];
  const int* labels = (const int*)d_in[2];
  float* out = (float*)d_out;
  char* ws = (char*)d_ws;

  unsigned int* zbf    = (unsigned int*)(ws);
  uint2* labs8         = (uint2*)(ws + 2097152);
  int* s               = (int*)(ws + 4194304);
  unsigned int* pm     = (unsigned int*)(ws + 4210688);
  float* part          = (float*)(ws + 6307840);

  hipLaunchKernelGGL(k_norm_pack, dim3(2048), dim3(256), 0, stream,
                     z1, z2, labels, zbf, labs8, s, out);
  hipLaunchKernelGGL(k_jac, dim3(32, 32), dim3(256), 0, stream,
                     (const unsigned char*)labs8, s, pm);
  hipLaunchKernelGGL(k_main, dim3(32, 64), dim3(256), 0, stream,
                     (const unsigned short*)zbf, pm, part);
  hipLaunchKernelGGL(k_loss, dim3(32), dim3(128), 0, stream, part, out);
}

// Round 6
// 111.696 us; speedup vs baseline: 1.2452x; 1.1487x over previous
//
#include <hip/hip_runtime.h>
#include <math.h>

#define N_ROWS 4096
#define DIM    128
#define A_LAB  512
#define INV_TAU 14.285714285714286f

typedef __attribute__((ext_vector_type(8))) short short8;   // 8 bf16 (4 VGPRs)
typedef __attribute__((ext_vector_type(4))) float f32x4;    // MFMA C/D frag (16x16)
typedef __attribute__((ext_vector_type(4))) int i32x4;      // i8 MFMA A/B frag
typedef __attribute__((ext_vector_type(16))) int i32x16;    // i8 MFMA C/D frag (32x32)

// ---------------- workspace layout (bytes) ----------------
// zbf   u16 [8192*128]   @ 0          (2,097,152)  unit-permuted (see k_norm_pack)
// labs8 i8  [4096*512]   @ 2,097,152  (2,097,152)  unit-permuted (see k_norm_pack)
// s     i32 [4096]       @ 4,194,304  (16,384)
// part  f32 [3*4096]     @ 4,210,688  (49,152)     atomically accumulated
//                                                   total ~4.26 MB

__device__ __forceinline__ unsigned short f2bf(float f) {
  unsigned int u = __builtin_bit_cast(unsigned int, f);
  u += 0x7fffu + ((u >> 16) & 1u);            // round-to-nearest-even
  return (unsigned short)(u >> 16);
}

// async global->LDS DMA, 16 B/lane; LDS dest = wave-uniform base + lane*16
__device__ __forceinline__ void gl_lds16(const void* g, void* l) {
  __builtin_amdgcn_global_load_lds(
      (const __attribute__((address_space(1))) unsigned int*)g,
      (__attribute__((address_space(3))) unsigned int*)l, 16, 0, 0);
}

// ------------ kernel 1: L2-normalize (-> bf16) + labels -> i8 + row-popcount ------------
// zbf rows: 16 units of 16 B, stored PERMUTED (unit U at slot U ^ (r&15)).
// labs8 rows: 32 units, permuted within 8-unit chunks ((c,u) at (c, u ^ (r&7))).
// Linear global_load_lds then reproduces the XOR-swizzled LDS layout readers expect.
// Also zeroes part[] and out[] for the downstream atomic accumulations.
__global__ __launch_bounds__(256) void k_norm_pack(
    const float* __restrict__ z1, const float* __restrict__ z2,
    const int* __restrict__ labels,
    unsigned int* __restrict__ zbf, uint2* __restrict__ labs8,
    int* __restrict__ s, float* __restrict__ part, float* __restrict__ out)
{
  {
    const int idx = blockIdx.x * 256 + threadIdx.x;
    if (idx < 3 * 4096) part[idx] = 0.0f;
    if (idx == 0) out[0] = 0.0f;
  }
  const int wave = threadIdx.x >> 6, lane = threadIdx.x & 63;
  const int r = blockIdx.x * 4 + wave;         // 0..8191
  const float* src = (r < N_ROWS) ? (z1 + (size_t)r * DIM)
                                  : (z2 + (size_t)(r - N_ROWS) * DIM);
  float2 x = ((const float2*)src)[lane];
  float ss = x.x * x.x + x.y * x.y;
  #pragma unroll
  for (int off = 32; off > 0; off >>= 1) ss += __shfl_xor(ss, off);
  const float inv = 1.0f / fmaxf(sqrtf(ss), 1e-12f);
  const unsigned int lo = f2bf(x.x * inv);
  const unsigned int hi = f2bf(x.y * inv);
  {
    const int U  = lane >> 2;                  // source 16B unit 0..15
    const int Up = U ^ (r & 15);               // permuted slot
    zbf[(size_t)r * 64 + Up * 4 + (lane & 3)] = (hi << 16) | lo;
  }

  if (r < N_ROWS) {
    const int4* lp = (const int4*)(labels + (size_t)r * A_LAB);
    const int4 a = lp[2 * lane], b = lp[2 * lane + 1];
    const unsigned int w0 = (unsigned int)(a.x != 0)       | ((unsigned int)(a.y != 0) << 8)
                          | ((unsigned int)(a.z != 0) << 16) | ((unsigned int)(a.w != 0) << 24);
    const unsigned int w1 = (unsigned int)(b.x != 0)       | ((unsigned int)(b.y != 0) << 8)
                          | ((unsigned int)(b.z != 0) << 16) | ((unsigned int)(b.w != 0) << 24);
    uint2 v; v.x = w0; v.y = w1;
    const int Ul  = lane >> 1;                 // source unit 0..31
    const int cc  = Ul >> 3, uu = Ul & 7;
    const int Ulp = (cc << 3) | (uu ^ (r & 7));
    labs8[(size_t)r * 64 + Ulp * 2 + (lane & 1)] = v;
    int cnt = __popc(w0) + __popc(w1);         // bytes are 0/1 -> popc == byte sum
    #pragma unroll
    for (int off = 32; off > 0; off >>= 1) cnt += __shfl_xor(cnt, off);
    if (lane == 0) s[r] = cnt;
  }
}

// ------------ kernel 2: FUSED jaccard-mask + sim-GEMM + masked-softmax partials ------------
// Block (bi,bj) owns anchors [128bi,128bi+128) x cols {[128bj..+128), [4096+128bj..+128)}.
// Phase J: i8 MFMA 128x128 Jaccard tile (dbuf async staging), threshold
//   13*inter >= 3*(si+sj) exact, ballot -> pos-bits in LDS (pmL, 2 KB). pm never
//   round-trips through global.
// Phase S: bf16 MFMA sim tiles vs both column halves (A staged once; B2
//   DMA-prefetched under half-0 epilogue), fixed softmax shift m=1/tau,
//   per-anchor (l, S, P) partials atomically added into part[3][4096].
__global__ __launch_bounds__(256, 2) void k_fused(
    const unsigned char* __restrict__ labs8, const int* __restrict__ s,
    const unsigned short* __restrict__ zbf, float* __restrict__ part)
{
  __shared__ uint4 lds[4096];                 // 64 KB: jac dbuf, then sim A|B
  __shared__ unsigned int pmL[128 * 4];       // pos-bits: [local row][col word]
  const int tid = threadIdx.x;
  const int ibase = blockIdx.x * 128, jbase = blockIdx.y * 128;
  const int wave = tid >> 6, lane = tid & 63;

  // ---------------- phase J: jaccard ----------------
  const int jwr = (wave >> 1) * 64, jwc = (wave & 1) * 64;   // 2x2 wave grid
  const int col32 = lane & 31, h = lane >> 5;

  const int s3i = 3 * s[ibase + jwr + lane];  // epilogue s-cache (via __shfl)
  const int s3j = 3 * s[jbase + jwc + lane];

  // stage labs chunk 0 into buf 0
  #pragma unroll
  for (int it = 0; it < 4; ++it) {
    const int g = wave * 256 + it * 64 + lane;   // linear unit 0..1023
    const int r = g >> 3, u = g & 7;
    gl_lds16(labs8 + (((size_t)(ibase + r)) << 9) + u * 16,
             &lds[wave * 256 + it * 64]);
    gl_lds16(labs8 + (((size_t)(jbase + r)) << 9) + u * 16,
             &lds[1024 + wave * 256 + it * 64]);
  }
  __syncthreads();

  i32x16 jacc[2][2];
  #pragma unroll
  for (int rt = 0; rt < 2; ++rt)
    #pragma unroll
    for (int nt = 0; nt < 2; ++nt)
      #pragma unroll
      for (int e = 0; e < 16; ++e) jacc[rt][nt][e] = 0;

  for (int ck = 0; ck < 4; ++ck) {            // K chunks of 128 bytes
    const int cur = (ck & 1) * 2048;
    if (ck < 3) {                             // prefetch next chunk into other buf
      const int nxt = ((ck + 1) & 1) * 2048;
      #pragma unroll
      for (int it = 0; it < 4; ++it) {
        const int g = wave * 256 + it * 64 + lane;
        const int r = g >> 3, u = g & 7;
        const size_t go = (size_t)(ck + 1) * 128 + u * 16;
        gl_lds16(labs8 + (((size_t)(ibase + r)) << 9) + go,
                 &lds[nxt + wave * 256 + it * 64]);
        gl_lds16(labs8 + (((size_t)(jbase + r)) << 9) + go,
                 &lds[nxt + 1024 + wave * 256 + it * 64]);
      }
    }
    #pragma unroll
    for (int ks = 0; ks < 4; ++ks) {          // 32 k-bytes per step
      const int u = ks * 2 + h;
      i32x4 a[2], b[2];
      #pragma unroll
      for (int rt = 0; rt < 2; ++rt) {
        const int m = jwr + rt * 32 + col32;
        a[rt] = *(const i32x4*)&lds[cur + m * 8 + (u ^ (m & 7))];
      }
      #pragma unroll
      for (int nt = 0; nt < 2; ++nt) {
        const int m = jwc + nt * 32 + col32;
        b[nt] = *(const i32x4*)&lds[cur + 1024 + m * 8 + (u ^ (m & 7))];
      }
      #pragma unroll
      for (int rt = 0; rt < 2; ++rt)
        #pragma unroll
        for (int nt = 0; nt < 2; ++nt)
          jacc[rt][nt] = __builtin_amdgcn_mfma_i32_32x32x32_i8(a[rt], b[nt], jacc[rt][nt], 0, 0, 0);
    }
    if (ck < 3) __syncthreads();
  }

  __syncthreads();   // all labs LDS reads done -> safe to overwrite with zbf

  // issue async staging of sim A-tile + B-left tile (overlaps jac epilogue)
  {
    const char* gz = (const char*)zbf;
    #pragma unroll
    for (int it = 0; it < 8; ++it) {
      const int g = wave * 512 + it * 64 + lane;   // linear unit 0..2047
      const int r = g >> 4, u = g & 15;
      gl_lds16(gz + (size_t)(ibase + r) * 256 + u * 16, &lds[wave * 512 + it * 64]);
      gl_lds16(gz + (size_t)(jbase + r) * 256 + u * 16, &lds[2048 + wave * 512 + it * 64]);
    }
  }

  // jac epilogue: threshold + ballot -> pmL (LDS only)
  #pragma unroll
  for (int rt = 0; rt < 2; ++rt)
    #pragma unroll
    for (int nt = 0; nt < 2; ++nt) {
      const int wl = (jwc >> 5) + nt;
      const int sj = __shfl(s3j, nt * 32 + col32);
      #pragma unroll
      for (int reg = 0; reg < 16; ++reg) {
        const int r0 = (reg & 3) + 8 * (reg >> 2);
        const int si = __shfl(s3i, rt * 32 + r0 + 4 * h);
        const bool pred = 13 * jacc[rt][nt][reg] >= si + sj;
        const unsigned long long bal = __ballot(pred);
        const int lr = jwr + rt * 32 + r0;
        if (lane == 0)      pmL[lr * 4 + wl]       = (unsigned int)bal;
        else if (lane == 1) pmL[(lr + 4) * 4 + wl] = (unsigned int)(bal >> 32);
      }
    }

  __syncthreads();   // zbf DMA drained + pmL visible

  // ---------------- phase S: similarity + softmax partials ----------------
  const int col = lane & 15, quad = lane >> 4;
  const int swr = wave * 32;                     // this wave: rows [swr, swr+32)
  const uint4* sAu = lds;
  const uint4* sBu = lds + 2048;

  short8 afr[2][4];
  #pragma unroll
  for (int rt = 0; rt < 2; ++rt)
    #pragma unroll
    for (int kf = 0; kf < 4; ++kf) {
      const int r = swr + rt * 16 + col;
      const int u = kf * 4 + quad;
      afr[rt][kf] = *(const short8*)&sAu[r * 16 + (u ^ (r & 15))];
    }

  float lacc[2][4], Sacc[2][4], Pcnt[2][4];
  #pragma unroll
  for (int rt = 0; rt < 2; ++rt)
    #pragma unroll
    for (int reg = 0; reg < 4; ++reg) { lacc[rt][reg] = 0; Sacc[rt][reg] = 0; Pcnt[rt][reg] = 0; }

  #pragma unroll
  for (int half = 0; half < 2; ++half) {
    f32x4 acc[2][8];
    #pragma unroll
    for (int rt = 0; rt < 2; ++rt)
      #pragma unroll
      for (int nt = 0; nt < 8; ++nt) acc[rt][nt] = (f32x4){0, 0, 0, 0};

    #pragma unroll
    for (int nt = 0; nt < 8; ++nt) {
      short8 bfr[4];
      #pragma unroll
      for (int kf = 0; kf < 4; ++kf) {
        const int r = nt * 16 + col;
        const int u = kf * 4 + quad;
        bfr[kf] = *(const short8*)&sBu[r * 16 + (u ^ (r & 15))];
      }
      #pragma unroll
      for (int rt = 0; rt < 2; ++rt)
        #pragma unroll
        for (int kf = 0; kf < 4; ++kf)
          acc[rt][nt] = __builtin_amdgcn_mfma_f32_16x16x32_bf16(
              afr[rt][kf], bfr[kf], acc[rt][nt], 0, 0, 0);
    }

    if (half == 0) {
      __syncthreads();   // all B1 reads done
      const char* gz = (const char*)zbf;
      #pragma unroll
      for (int it = 0; it < 8; ++it) {   // B2 = right-half columns (z2n rows)
        const int g = wave * 512 + it * 64 + lane;
        const int r = g >> 4, u = g & 15;
        gl_lds16(gz + (size_t)(N_ROWS + jbase + r) * 256 + u * 16,
                 &lds[2048 + wave * 512 + it * 64]);
      }
    }

    // epilogue: fixed shift m = 1/tau; self col excluded (left half only)
    const bool left = (half == 0);
    #pragma unroll
    for (int rt = 0; rt < 2; ++rt) {
      unsigned int pw[4][4];
      #pragma unroll
      for (int reg = 0; reg < 4; ++reg) {
        const int li = swr + rt * 16 + quad * 4 + reg;
        #pragma unroll
        for (int w = 0; w < 4; ++w) pw[reg][w] = pmL[li * 4 + w];
      }
      #pragma unroll
      for (int nt = 0; nt < 8; ++nt) {
        const int joff = nt * 16 + col;            // 0..127 within tile
        const int jc = jbase + joff;               // column mod N
        const int bitpos = joff & 31;
        const int w = nt >> 1;
        #pragma unroll
        for (int reg = 0; reg < 4; ++reg) {
          const int i = ibase + swr + rt * 16 + quad * 4 + reg;
          const float d = acc[rt][nt][reg];
          const bool bit = (pw[reg][w] >> bitpos) & 1;
          const bool self = left && (jc == i);
          const bool pos = left ? (bit && !self) : (bit || (jc == i));
          const float e = __expf((d - 1.0f) * INV_TAU);
          if (!self) lacc[rt][reg] += e;
          if (pos) { Sacc[rt][reg] += d; Pcnt[rt][reg] += 1.0f; }
        }
      }
    }
    if (half == 0) __syncthreads();   // B2 landed
  }

  // ---- reduce across the 16 col-lanes, atomically accumulate per-anchor ----
  #pragma unroll
  for (int rt = 0; rt < 2; ++rt)
    #pragma unroll
    for (int reg = 0; reg < 4; ++reg) {
      float l = lacc[rt][reg], S = Sacc[rt][reg], P = Pcnt[rt][reg];
      #pragma unroll
      for (int m = 1; m < 16; m <<= 1) {
        l += __shfl_xor(l, m);
        S += __shfl_xor(S, m);
        P += __shfl_xor(P, m);
      }
      if (col == 0) {
        const int i = ibase + swr + rt * 16 + quad * 4 + reg;
        atomicAdd(&part[i], l);
        atomicAdd(&part[4096 + i], S);
        atomicAdd(&part[8192 + i], P);
      }
    }
}

// ---------------- kernel 3: per-anchor loss + atomic final reduce ----------------
__global__ __launch_bounds__(128) void k_loss(
    const float* __restrict__ part, float* __restrict__ out)
{
  const int a = blockIdx.x * 128 + threadIdx.x;   // 0..4095
  const float l = part[a];
  const float S = part[4096 + a];
  const float P = part[8192 + a];
  const float np = fmaxf(P, 1.0f);
  float v = INV_TAU + logf(l + 1e-8f) - (S * INV_TAU) / np;
  #pragma unroll
  for (int off = 32; off > 0; off >>= 1) v += __shfl_xor(v, off);
  __shared__ float ws2[2];
  const int wave = threadIdx.x >> 6, lane = threadIdx.x & 63;
  if (lane == 0) ws2[wave] = v;
  __syncthreads();
  if (threadIdx.x == 0) atomicAdd(out, (ws2[0] + ws2[1]) * (1.0f / (float)N_ROWS));
}

extern "C" void kernel_launch(void* const* d_in, const int* in_sizes, int n_in,
                              void* d_out, int out_size, void* d_ws, size_t ws_size,
                              hipStream_t stream) {
  const float* z1 = (const float*)d_in[0];
  const float* z2 = (const float*)d_in[1];
  const int* labels = (const int*)d_in[2];
  float* out = (float*)d_out;
  char* ws = (char*)d_ws;

  unsigned int* zbf    = (unsigned int*)(ws);
  uint2* labs8         = (uint2*)(ws + 2097152);
  int* s               = (int*)(ws + 4194304);
  float* part          = (float*)(ws + 4210688);

  hipLaunchKernelGGL(k_norm_pack, dim3(2048), dim3(256), 0, stream,
                     z1, z2, labels, zbf, labs8, s, part, out);
  hipLaunchKernelGGL(k_fused, dim3(32, 32), dim3(256), 0, stream,
                     (const unsigned char*)labs8, s, (const unsigned short*)zbf, part);
  hipLaunchKernelGGL(k_loss, dim3(32), dim3(128), 0, stream, part, out);
}

// Round 7
// 109.388 us; speedup vs baseline: 1.2714x; 1.0211x over previous
//
#include <hip/hip_runtime.h>
#include <math.h>

#define N_ROWS 4096
#define DIM    128
#define A_LAB  512
#define INV_TAU 14.285714285714286f
#define C_EXP   20.609929155556620f   // INV_TAU * log2(e)

typedef __attribute__((ext_vector_type(8))) short short8;   // 8 bf16 (4 VGPRs)
typedef __attribute__((ext_vector_type(4))) float f32x4;    // MFMA C/D frag (16x16)
typedef __attribute__((ext_vector_type(4))) int i32x4;      // i8 MFMA A/B frag
typedef __attribute__((ext_vector_type(16))) int i32x16;    // i8 MFMA C/D frag (32x32)

// ---------------- workspace layout (bytes) ----------------
// zbf   u16 [8192*128]   @ 0          (2,097,152)  unit-permuted (see k_norm_pack)
// labs8 i8  [4096*512]   @ 2,097,152  (2,097,152)  unit-permuted (see k_norm_pack)
// s     i32 [4096]       @ 4,194,304  (16,384)
// part  f32 [3*4096]     @ 4,210,688  (49,152)     atomically accumulated

__device__ __forceinline__ unsigned short f2bf(float f) {
  unsigned int u = __builtin_bit_cast(unsigned int, f);
  u += 0x7fffu + ((u >> 16) & 1u);            // round-to-nearest-even
  return (unsigned short)(u >> 16);
}

// async global->LDS DMA, 16 B/lane; LDS dest = wave-uniform base + lane*16
__device__ __forceinline__ void gl_lds16(const void* g, void* l) {
  __builtin_amdgcn_global_load_lds(
      (const __attribute__((address_space(1))) unsigned int*)g,
      (__attribute__((address_space(3))) unsigned int*)l, 16, 0, 0);
}

// ------------ kernel 1: L2-normalize (-> bf16) + labels -> i8 + row-popcount ------------
// zbf rows: 16 units of 16 B, stored PERMUTED (unit U at slot U ^ (r&15)).
// labs8 rows: 32 units, permuted within 8-unit chunks ((c,u) at (c, u ^ (r&7))).
// Linear global_load_lds then reproduces the XOR-swizzled LDS layout readers expect.
// Also zeroes part[] and out[] for the downstream atomic accumulations.
__global__ __launch_bounds__(256) void k_norm_pack(
    const float* __restrict__ z1, const float* __restrict__ z2,
    const int* __restrict__ labels,
    unsigned int* __restrict__ zbf, uint2* __restrict__ labs8,
    int* __restrict__ s, float* __restrict__ part, float* __restrict__ out)
{
  {
    const int idx = blockIdx.x * 256 + threadIdx.x;
    if (idx < 3 * 4096) part[idx] = 0.0f;
    if (idx == 0) out[0] = 0.0f;
  }
  const int wave = threadIdx.x >> 6, lane = threadIdx.x & 63;
  const int r = blockIdx.x * 4 + wave;         // 0..8191
  const float* src = (r < N_ROWS) ? (z1 + (size_t)r * DIM)
                                  : (z2 + (size_t)(r - N_ROWS) * DIM);
  float2 x = ((const float2*)src)[lane];
  float ss = x.x * x.x + x.y * x.y;
  #pragma unroll
  for (int off = 32; off > 0; off >>= 1) ss += __shfl_xor(ss, off);
  const float inv = 1.0f / fmaxf(sqrtf(ss), 1e-12f);
  const unsigned int lo = f2bf(x.x * inv);
  const unsigned int hi = f2bf(x.y * inv);
  {
    const int U  = lane >> 2;                  // source 16B unit 0..15
    const int Up = U ^ (r & 15);               // permuted slot
    zbf[(size_t)r * 64 + Up * 4 + (lane & 3)] = (hi << 16) | lo;
  }

  if (r < N_ROWS) {
    const int4* lp = (const int4*)(labels + (size_t)r * A_LAB);
    const int4 a = lp[2 * lane], b = lp[2 * lane + 1];
    const unsigned int w0 = (unsigned int)(a.x != 0)       | ((unsigned int)(a.y != 0) << 8)
                          | ((unsigned int)(a.z != 0) << 16) | ((unsigned int)(a.w != 0) << 24);
    const unsigned int w1 = (unsigned int)(b.x != 0)       | ((unsigned int)(b.y != 0) << 8)
                          | ((unsigned int)(b.z != 0) << 16) | ((unsigned int)(b.w != 0) << 24);
    uint2 v; v.x = w0; v.y = w1;
    const int Ul  = lane >> 1;                 // source unit 0..31
    const int cc  = Ul >> 3, uu = Ul & 7;
    const int Ulp = (cc << 3) | (uu ^ (r & 7));
    labs8[(size_t)r * 64 + Ulp * 2 + (lane & 1)] = v;
    int cnt = __popc(w0) + __popc(w1);         // bytes are 0/1 -> popc == byte sum
    #pragma unroll
    for (int off = 32; off > 0; off >>= 1) cnt += __shfl_xor(cnt, off);
    if (lane == 0) s[r] = cnt;
  }
}

// ------------ kernel 2: FUSED jaccard-mask + sim-GEMM + masked-softmax partials ------------
// Block (bi,bj): anchors [128bi..+128) x cols {[128bj..+128), [4096+128bj..+128)}.
// LDS budget 34 KB -> 3 blocks/CU (launch_bounds(256,3)).
// Phase J: i8 MFMA Jaccard tile, single 32 KB LDS buffer, 4 K-chunks; exact
//   threshold 13*inter >= 3*(si+sj); ballot -> pos-bits in pmL (2 KB LDS).
// Phase S: bf16 MFMA sim; A-fragments read DIRECTLY from global zbf (slot
//   inversion of the pre-permute), B tiles DMA'd into the same 32 KB buffer,
//   B2 prefetched under half-0 epilogue. Off-diagonal blocks use a slimmed
//   epilogue (no self/aug logic). Partials atomically added into part[3][4096].
__global__ __launch_bounds__(256, 3) void k_fused(
    const unsigned char* __restrict__ labs8, const int* __restrict__ s,
    const unsigned short* __restrict__ zbf, float* __restrict__ part)
{
  __shared__ uint4 lds[2048];                 // 32 KB shared stage (jac, then B)
  __shared__ unsigned int pmL[128 * 4];       // pos-bits: [local row][col word]
  const int tid = threadIdx.x;
  const int ibase = blockIdx.x * 128, jbase = blockIdx.y * 128;
  const int wave = tid >> 6, lane = tid & 63;
  const bool diag = (ibase == jbase);

  // ---------------- phase J: jaccard ----------------
  const int jwr = (wave >> 1) * 64, jwc = (wave & 1) * 64;   // 2x2 wave grid
  const int col32 = lane & 31, h = lane >> 5;

  const int s3i = 3 * s[ibase + jwr + lane];  // epilogue s-cache (via __shfl)
  const int s3j = 3 * s[jbase + jwc + lane];

  i32x16 jacc[2][2];
  #pragma unroll
  for (int rt = 0; rt < 2; ++rt)
    #pragma unroll
    for (int nt = 0; nt < 2; ++nt)
      #pragma unroll
      for (int e = 0; e < 16; ++e) jacc[rt][nt][e] = 0;

  for (int ck = 0; ck < 4; ++ck) {            // K chunks of 128 bytes
    if (ck) __syncthreads();                  // prior chunk's reads done
    #pragma unroll
    for (int it = 0; it < 4; ++it) {
      const int g = wave * 256 + it * 64 + lane;   // linear unit 0..1023
      const int r = g >> 3, u = g & 7;
      const size_t go = (size_t)ck * 128 + u * 16;
      gl_lds16(labs8 + (((size_t)(ibase + r)) << 9) + go,
               &lds[wave * 256 + it * 64]);
      gl_lds16(labs8 + (((size_t)(jbase + r)) << 9) + go,
               &lds[1024 + wave * 256 + it * 64]);
    }
    __syncthreads();                          // DMA landed
    #pragma unroll
    for (int ks = 0; ks < 4; ++ks) {          // 32 k-bytes per step
      const int u = ks * 2 + h;
      i32x4 a[2], b[2];
      #pragma unroll
      for (int rt = 0; rt < 2; ++rt) {
        const int m = jwr + rt * 32 + col32;
        a[rt] = *(const i32x4*)&lds[m * 8 + (u ^ (m & 7))];
      }
      #pragma unroll
      for (int nt = 0; nt < 2; ++nt) {
        const int m = jwc + nt * 32 + col32;
        b[nt] = *(const i32x4*)&lds[1024 + m * 8 + (u ^ (m & 7))];
      }
      #pragma unroll
      for (int rt = 0; rt < 2; ++rt)
        #pragma unroll
        for (int nt = 0; nt < 2; ++nt)
          jacc[rt][nt] = __builtin_amdgcn_mfma_i32_32x32x32_i8(a[rt], b[nt], jacc[rt][nt], 0, 0, 0);
    }
  }

  __syncthreads();   // all labs LDS reads done -> safe to overwrite with B1

  // B1 DMA (left-half columns) into lds; overlaps jac epilogue below
  {
    const char* gz = (const char*)zbf;
    #pragma unroll
    for (int it = 0; it < 8; ++it) {
      const int g = wave * 512 + it * 64 + lane;   // linear unit 0..2047
      const int r = g >> 4, u = g & 15;
      gl_lds16(gz + (size_t)(jbase + r) * 256 + u * 16, &lds[wave * 512 + it * 64]);
    }
  }

  // A-fragments straight from global (pre-permuted zbf; slot = U ^ (r&15))
  const int col = lane & 15, quad = lane >> 4;
  const int swr = wave * 32;                     // this wave: rows [swr, swr+32)
  short8 afr[2][4];
  {
    const char* gz = (const char*)zbf;
    #pragma unroll
    for (int rt = 0; rt < 2; ++rt)
      #pragma unroll
      for (int kf = 0; kf < 4; ++kf) {
        const int ra = ibase + swr + rt * 16 + col;
        const int slot = (kf * 4 + quad) ^ (ra & 15);
        afr[rt][kf] = *(const short8*)(gz + (size_t)ra * 256 + slot * 16);
      }
  }

  // jac epilogue: threshold + ballot -> pmL (LDS only)
  #pragma unroll
  for (int rt = 0; rt < 2; ++rt)
    #pragma unroll
    for (int nt = 0; nt < 2; ++nt) {
      const int wl = (jwc >> 5) + nt;
      const int sj = __shfl(s3j, nt * 32 + col32);
      #pragma unroll
      for (int reg = 0; reg < 16; ++reg) {
        const int r0 = (reg & 3) + 8 * (reg >> 2);
        const int si = __shfl(s3i, rt * 32 + r0 + 4 * h);
        const bool pred = 13 * jacc[rt][nt][reg] >= si + sj;
        const unsigned long long bal = __ballot(pred);
        const int lr = jwr + rt * 32 + r0;
        if (lane == 0)      pmL[lr * 4 + wl]       = (unsigned int)bal;
        else if (lane == 1) pmL[(lr + 4) * 4 + wl] = (unsigned int)(bal >> 32);
      }
    }

  __syncthreads();   // B1 DMA drained + pmL visible

  // ---------------- phase S: similarity + softmax partials ----------------
  float lacc[2][4], Sacc[2][4], Pcnt[2][4];
  #pragma unroll
  for (int rt = 0; rt < 2; ++rt)
    #pragma unroll
    for (int reg = 0; reg < 4; ++reg) { lacc[rt][reg] = 0; Sacc[rt][reg] = 0; Pcnt[rt][reg] = 0; }

  #pragma unroll
  for (int half = 0; half < 2; ++half) {
    f32x4 acc[2][8];
    #pragma unroll
    for (int rt = 0; rt < 2; ++rt)
      #pragma unroll
      for (int nt = 0; nt < 8; ++nt) acc[rt][nt] = (f32x4){0, 0, 0, 0};

    #pragma unroll
    for (int nt = 0; nt < 8; ++nt) {
      short8 bfr[4];
      #pragma unroll
      for (int kf = 0; kf < 4; ++kf) {
        const int r = nt * 16 + col;
        const int u = kf * 4 + quad;
        bfr[kf] = *(const short8*)&lds[r * 16 + (u ^ (r & 15))];
      }
      #pragma unroll
      for (int rt = 0; rt < 2; ++rt)
        #pragma unroll
        for (int kf = 0; kf < 4; ++kf)
          acc[rt][nt] = __builtin_amdgcn_mfma_f32_16x16x32_bf16(
              afr[rt][kf], bfr[kf], acc[rt][nt], 0, 0, 0);
    }

    if (half == 0) {
      __syncthreads();   // all B1 reads done
      const char* gz = (const char*)zbf;
      #pragma unroll
      for (int it = 0; it < 8; ++it) {   // B2 = right-half columns (z2n rows)
        const int g = wave * 512 + it * 64 + lane;
        const int r = g >> 4, u = g & 15;
        gl_lds16(gz + (size_t)(N_ROWS + jbase + r) * 256 + u * 16,
                 &lds[wave * 512 + it * 64]);
      }
    }

    // epilogue: fixed shift m = 1/tau (loss shift-invariant)
    if (!diag) {
      // off-diagonal: no self column, no forced aug column -> slim path
      #pragma unroll
      for (int rt = 0; rt < 2; ++rt) {
        unsigned int pw[4][4];
        #pragma unroll
        for (int reg = 0; reg < 4; ++reg) {
          const int li = swr + rt * 16 + quad * 4 + reg;
          #pragma unroll
          for (int w = 0; w < 4; ++w) pw[reg][w] = pmL[li * 4 + w];
        }
        #pragma unroll
        for (int nt = 0; nt < 8; ++nt) {
          const int joff = nt * 16 + col;          // 0..127 within tile
          const int bitpos = joff & 31;
          const int w = nt >> 1;
          #pragma unroll
          for (int reg = 0; reg < 4; ++reg) {
            const float d = acc[rt][nt][reg];
            const bool bit = (pw[reg][w] >> bitpos) & 1;
            lacc[rt][reg] += exp2f(fmaf(d, C_EXP, -C_EXP));
            if (bit) { Sacc[rt][reg] += d; Pcnt[rt][reg] += 1.0f; }
          }
        }
      }
    } else {
      const bool left = (half == 0);
      #pragma unroll
      for (int rt = 0; rt < 2; ++rt) {
        unsigned int pw[4][4];
        #pragma unroll
        for (int reg = 0; reg < 4; ++reg) {
          const int li = swr + rt * 16 + quad * 4 + reg;
          #pragma unroll
          for (int w = 0; w < 4; ++w) pw[reg][w] = pmL[li * 4 + w];
        }
        #pragma unroll
        for (int nt = 0; nt < 8; ++nt) {
          const int joff = nt * 16 + col;
          const int jc = jbase + joff;             // column mod N
          const int bitpos = joff & 31;
          const int w = nt >> 1;
          #pragma unroll
          for (int reg = 0; reg < 4; ++reg) {
            const int i = ibase + swr + rt * 16 + quad * 4 + reg;
            const float d = acc[rt][nt][reg];
            const bool bit = (pw[reg][w] >> bitpos) & 1;
            const bool self = left && (jc == i);
            const bool pos = left ? (bit && !self) : (bit || (jc == i));
            const float e = exp2f(fmaf(d, C_EXP, -C_EXP));
            if (!self) lacc[rt][reg] += e;
            if (pos) { Sacc[rt][reg] += d; Pcnt[rt][reg] += 1.0f; }
          }
        }
      }
    }
    if (half == 0) __syncthreads();   // B2 landed
  }

  // ---- reduce across the 16 col-lanes, atomically accumulate per-anchor ----
  #pragma unroll
  for (int rt = 0; rt < 2; ++rt)
    #pragma unroll
    for (int reg = 0; reg < 4; ++reg) {
      float l = lacc[rt][reg], S = Sacc[rt][reg], P = Pcnt[rt][reg];
      #pragma unroll
      for (int m = 1; m < 16; m <<= 1) {
        l += __shfl_xor(l, m);
        S += __shfl_xor(S, m);
        P += __shfl_xor(P, m);
      }
      if (col == 0) {
        const int i = ibase + swr + rt * 16 + quad * 4 + reg;
        atomicAdd(&part[i], l);
        atomicAdd(&part[4096 + i], S);
        atomicAdd(&part[8192 + i], P);
      }
    }
}

// ---------------- kernel 3: per-anchor loss + atomic final reduce ----------------
__global__ __launch_bounds__(128) void k_loss(
    const float* __restrict__ part, float* __restrict__ out)
{
  const int a = blockIdx.x * 128 + threadIdx.x;   // 0..4095
  const float l = part[a];
  const float S = part[4096 + a];
  const float P = part[8192 + a];
  const float np = fmaxf(P, 1.0f);
  float v = INV_TAU + logf(l + 1e-8f) - (S * INV_TAU) / np;
  #pragma unroll
  for (int off = 32; off > 0; off >>= 1) v += __shfl_xor(v, off);
  __shared__ float ws2[2];
  const int wave = threadIdx.x >> 6, lane = threadIdx.x & 63;
  if (lane == 0) ws2[wave] = v;
  __syncthreads();
  if (threadIdx.x == 0) atomicAdd(out, (ws2[0] + ws2[1]) * (1.0f / (float)N_ROWS));
}

extern "C" void kernel_launch(void* const* d_in, const int* in_sizes, int n_in,
                              void* d_out, int out_size, void* d_ws, size_t ws_size,
                              hipStream_t stream) {
  const float* z1 = (const float*)d_in[0];
  const float* z2 = (const float*)d_in[1];
  const int* labels = (const int*)d_in[2];
  float* out = (float*)d_out;
  char* ws = (char*)d_ws;

  unsigned int* zbf    = (unsigned int*)(ws);
  uint2* labs8         = (uint2*)(ws + 2097152);
  int* s               = (int*)(ws + 4194304);
  float* part          = (float*)(ws + 4210688);

  hipLaunchKernelGGL(k_norm_pack, dim3(2048), dim3(256), 0, stream,
                     z1, z2, labels, zbf, labs8, s, part, out);
  hipLaunchKernelGGL(k_fused, dim3(32, 32), dim3(256), 0, stream,
                     (const unsigned char*)labs8, s, (const unsigned short*)zbf, part);
  hipLaunchKernelGGL(k_loss, dim3(32), dim3(128), 0, stream, part, out);
}